// Round 1
// baseline (239.751 us; speedup 1.0000x reference)
//
#include <hip/hip_runtime.h>

#define DD 160
#define HH 160
#define WW 160
#define HT 8            // output rows (h) per block
#define HS (HT + 8)     // staged rows  = 16
#define WP (WW + 8)     // padded row width = 168
#define VOL (DD * HH * WW)   // per-batch volume = 4,096,000
#define NB 2
#define CCBLOCKS 2048
#define GBLOCKS 2048

// ---------------------------------------------------------------------------
// Kernel 1: fused W-window + H-window box sums of the 5 moment fields
//   fields: 0:sum(m) 1:sum(f) 2:sum(m*m) 3:sum(f*f) 4:sum(m*f)
// One block per (h-tile, d). Zero padding (matches conv zero-pad semantics).
// ---------------------------------------------------------------------------
__global__ __launch_bounds__(256) void ncc_wh(const float* __restrict__ mv,
                                              const float* __restrict__ fx,
                                              float* __restrict__ out) {
    __shared__ float sm[HS][WP];
    __shared__ float sf[HS][WP];
    __shared__ float wsum[3][HS][WW];   // reused: group1 uses 3, group2 uses 2

    const int ht  = blockIdx.x;         // 0..19
    const int d   = blockIdx.y;         // 0..159
    const int h0  = ht * HT;
    const int tid = threadIdx.x;

    // stage rows h0-4 .. h0+HT+3, zero-padded in h and w
    for (int i = tid; i < HS * WP; i += 256) {
        int r = i / WP, c = i - r * WP;
        int h = h0 - 4 + r, w = c - 4;
        float m = 0.f, f = 0.f;
        if ((unsigned)h < (unsigned)HH && (unsigned)w < (unsigned)WW) {
            int gi = (d * HH + h) * WW + w;
            m = mv[gi];
            f = fx[gi];
        }
        sm[r][c] = m;
        sf[r][c] = f;
    }
    __syncthreads();

    // ---- group 1: m, f, m*f -> fields 0,1,4 ----
    for (int i = tid; i < HS * WW; i += 256) {
        int r = i / WW, w = i - r * WW;
        float s0 = 0.f, s1 = 0.f, s2 = 0.f;
#pragma unroll
        for (int t = 0; t < 9; ++t) {
            float m = sm[r][w + t], f = sf[r][w + t];
            s0 += m; s1 += f; s2 += m * f;
        }
        wsum[0][r][w] = s0; wsum[1][r][w] = s1; wsum[2][r][w] = s2;
    }
    __syncthreads();
    for (int i = tid; i < HT * WW; i += 256) {
        int ro = i / WW, w = i - ro * WW;
        float a0 = 0.f, a1 = 0.f, a2 = 0.f;
#pragma unroll
        for (int t = 0; t < 9; ++t) {
            a0 += wsum[0][ro + t][w];
            a1 += wsum[1][ro + t][w];
            a2 += wsum[2][ro + t][w];
        }
        int go = (d * HH + h0 + ro) * WW + w;
        out[0 * VOL + go] = a0;
        out[1 * VOL + go] = a1;
        out[4 * VOL + go] = a2;
    }
    __syncthreads();

    // ---- group 2: m*m, f*f -> fields 2,3 ----
    for (int i = tid; i < HS * WW; i += 256) {
        int r = i / WW, w = i - r * WW;
        float s0 = 0.f, s1 = 0.f;
#pragma unroll
        for (int t = 0; t < 9; ++t) {
            float m = sm[r][w + t], f = sf[r][w + t];
            s0 += m * m; s1 += f * f;
        }
        wsum[0][r][w] = s0; wsum[1][r][w] = s1;
    }
    __syncthreads();
    for (int i = tid; i < HT * WW; i += 256) {
        int ro = i / WW, w = i - ro * WW;
        float a0 = 0.f, a1 = 0.f;
#pragma unroll
        for (int t = 0; t < 9; ++t) {
            a0 += wsum[0][ro + t][w];
            a1 += wsum[1][ro + t][w];
        }
        int go = (d * HH + h0 + ro) * WW + w;
        out[2 * VOL + go] = a0;
        out[3 * VOL + go] = a1;
    }
}

// ---------------------------------------------------------------------------
// Kernel 2: D-window sum of the 5 fields + per-voxel cc + block reduction
// ---------------------------------------------------------------------------
__global__ __launch_bounds__(256) void ncc_dred(const float* __restrict__ s5,
                                                float* __restrict__ partial) {
    float acc = 0.f;
    const int stride = gridDim.x * blockDim.x;
    for (int idx = blockIdx.x * blockDim.x + threadIdx.x; idx < VOL; idx += stride) {
        int d  = idx / (HH * WW);
        int hw = idx - d * (HH * WW);
        int lo = d > 4 ? d - 4 : 0;
        int hi = d < DD - 5 ? d + 4 : DD - 1;
        float s0 = 0.f, s1 = 0.f, s2 = 0.f, s3 = 0.f, s4 = 0.f;
        for (int dd = lo; dd <= hi; ++dd) {
            int gi = dd * (HH * WW) + hw;
            s0 += s5[0 * VOL + gi];
            s1 += s5[1 * VOL + gi];
            s2 += s5[2 * VOL + gi];
            s3 += s5[3 * VOL + gi];
            s4 += s5[4 * VOL + gi];
        }
        const float win = 729.0f;
        float up = s0 / win, ut = s1 / win;
        float cross = s4 - ut * s0 - up * s1 + up * ut * win;
        float pv = s2 - 2.0f * up * s0 + up * up * win;
        float tv = s3 - 2.0f * ut * s1 + ut * ut * win;
        pv = fmaxf(pv, 0.f);
        tv = fmaxf(tv, 0.f);
        float cc = cross * cross / (pv * tv + 0.001f);
        acc += fminf(fmaxf(cc, 0.f), 1.f);
    }
    // deterministic block reduction
    for (int o = 32; o > 0; o >>= 1) acc += __shfl_down(acc, o, 64);
    __shared__ float red[4];
    int lane = threadIdx.x & 63, wid = threadIdx.x >> 6;
    if (lane == 0) red[wid] = acc;
    __syncthreads();
    if (threadIdx.x == 0) partial[blockIdx.x] = red[0] + red[1] + red[2] + red[3];
}

// ---------------------------------------------------------------------------
// Kernel 3: L1 gradient penalty on flow (forward diffs along d,h,w)
// ---------------------------------------------------------------------------
__global__ __launch_bounds__(256) void grad_red(const float* __restrict__ fl,
                                                float* __restrict__ partial) {
    const int n = NB * 3 * VOL;   // 24,576,000
    float acc = 0.f;
    const int stride = gridDim.x * blockDim.x;
    for (int idx = blockIdx.x * blockDim.x + threadIdx.x; idx < n; idx += stride) {
        int w = idx % WW;
        int t = idx / WW;
        int h = t % HH;
        int d = (t / HH) % DD;
        float v = fl[idx];
        if (d < DD - 1) acc += fabsf(fl[idx + HH * WW] - v);
        if (h < HH - 1) acc += fabsf(fl[idx + WW] - v);
        if (w < WW - 1) acc += fabsf(fl[idx + 1] - v);
    }
    for (int o = 32; o > 0; o >>= 1) acc += __shfl_down(acc, o, 64);
    __shared__ float red[4];
    int lane = threadIdx.x & 63, wid = threadIdx.x >> 6;
    if (lane == 0) red[wid] = acc;
    __syncthreads();
    if (threadIdx.x == 0) partial[blockIdx.x] = red[0] + red[1] + red[2] + red[3];
}

// ---------------------------------------------------------------------------
// Kernel 4: final deterministic reduction of partials -> scalar loss
// ---------------------------------------------------------------------------
__global__ __launch_bounds__(256) void finalize(const float* __restrict__ pcc, int ncc,
                                                const float* __restrict__ pg, int ng,
                                                float* __restrict__ out) {
    __shared__ float red[4];
    int lane = threadIdx.x & 63, wid = threadIdx.x >> 6;

    float a = 0.f;
    for (int i = threadIdx.x; i < ncc; i += 256) a += pcc[i];
    for (int o = 32; o > 0; o >>= 1) a += __shfl_down(a, o, 64);
    if (lane == 0) red[wid] = a;
    __syncthreads();
    float asum = red[0] + red[1] + red[2] + red[3];
    __syncthreads();

    float g = 0.f;
    for (int i = threadIdx.x; i < ng; i += 256) g += pg[i];
    for (int o = 32; o > 0; o >>= 1) g += __shfl_down(g, o, 64);
    if (lane == 0) red[wid] = g;
    __syncthreads();
    float gsum = red[0] + red[1] + red[2] + red[3];

    if (threadIdx.x == 0) {
        float sim = 1.0f - asum / 8192000.0f;          // mean over (2,1,160,160,160)
        float reg = gsum / 73267200.0f;                // 3 * (2*3*159*160*160)
        out[0] = sim + reg;
    }
}

// ---------------------------------------------------------------------------
extern "C" void kernel_launch(void* const* d_in, const int* in_sizes, int n_in,
                              void* d_out, int out_size, void* d_ws, size_t ws_size,
                              hipStream_t stream) {
    const float* moved  = (const float*)d_in[0];
    const float* fixedp = (const float*)d_in[1];
    const float* flow   = (const float*)d_in[2];
    float* out = (float*)d_out;
    float* ws  = (float*)d_ws;

    float* fields = ws;                              // 5*VOL floats (81.9 MB)
    float* pcc    = ws + 5 * (size_t)VOL;            // NB*CCBLOCKS floats
    float* pg     = pcc + NB * CCBLOCKS;             // GBLOCKS floats

    grad_red<<<GBLOCKS, 256, 0, stream>>>(flow, pg);

    for (int b = 0; b < NB; ++b) {
        ncc_wh<<<dim3(HH / HT, DD), 256, 0, stream>>>(
            moved + (size_t)b * VOL, fixedp + (size_t)b * VOL, fields);
        ncc_dred<<<CCBLOCKS, 256, 0, stream>>>(fields, pcc + b * CCBLOCKS);
    }

    finalize<<<1, 256, 0, stream>>>(pcc, NB * CCBLOCKS, pg, GBLOCKS, out);
}

// Round 2
// 197.104 us; speedup vs baseline: 1.2164x; 1.2164x over previous
//
#include <hip/hip_runtime.h>

#define DD 160
#define HH 160
#define WW 160
#define HT 8            // output rows (h) per block in ncc_wh
#define HS (HT + 8)     // staged rows  = 16
#define WP (WW + 8)     // padded row width = 168
#define VOL (DD * HH * WW)   // per-batch volume = 4,096,000
#define PLANE (HH * WW)      // 25,600
#define NB 2
#define DCH 20               // d-outputs per ncc_dred block
#define NDCH (DD / DCH)      // 8
#define HWT (PLANE / 256)    // 100 hw-tiles
#define DREDBLK (HWT * NDCH) // 800 blocks per batch
#define GBLOCKS 2048

// ---------------------------------------------------------------------------
// Kernel 1: fused W-window + H-window box sums of the 5 moment fields
//   fields: 0:sum(m) 1:sum(f) 2:sum(m*m) 3:sum(f*f) 4:sum(m*f)
// ---------------------------------------------------------------------------
__global__ __launch_bounds__(256) void ncc_wh(const float* __restrict__ mv,
                                              const float* __restrict__ fx,
                                              float* __restrict__ out) {
    __shared__ float sm[HS][WP];
    __shared__ float sf[HS][WP];
    __shared__ float wsum[3][HS][WW];

    const int ht  = blockIdx.x;
    const int d   = blockIdx.y;
    const int h0  = ht * HT;
    const int tid = threadIdx.x;

    for (int i = tid; i < HS * WP; i += 256) {
        int r = i / WP, c = i - r * WP;
        int h = h0 - 4 + r, w = c - 4;
        float m = 0.f, f = 0.f;
        if ((unsigned)h < (unsigned)HH && (unsigned)w < (unsigned)WW) {
            int gi = (d * HH + h) * WW + w;
            m = mv[gi];
            f = fx[gi];
        }
        sm[r][c] = m;
        sf[r][c] = f;
    }
    __syncthreads();

    // group 1: m, f, m*f -> fields 0,1,4
    for (int i = tid; i < HS * WW; i += 256) {
        int r = i / WW, w = i - r * WW;
        float s0 = 0.f, s1 = 0.f, s2 = 0.f;
#pragma unroll
        for (int t = 0; t < 9; ++t) {
            float m = sm[r][w + t], f = sf[r][w + t];
            s0 += m; s1 += f; s2 += m * f;
        }
        wsum[0][r][w] = s0; wsum[1][r][w] = s1; wsum[2][r][w] = s2;
    }
    __syncthreads();
    for (int i = tid; i < HT * WW; i += 256) {
        int ro = i / WW, w = i - ro * WW;
        float a0 = 0.f, a1 = 0.f, a2 = 0.f;
#pragma unroll
        for (int t = 0; t < 9; ++t) {
            a0 += wsum[0][ro + t][w];
            a1 += wsum[1][ro + t][w];
            a2 += wsum[2][ro + t][w];
        }
        int go = (d * HH + h0 + ro) * WW + w;
        out[0 * VOL + go] = a0;
        out[1 * VOL + go] = a1;
        out[4 * VOL + go] = a2;
    }
    __syncthreads();

    // group 2: m*m, f*f -> fields 2,3
    for (int i = tid; i < HS * WW; i += 256) {
        int r = i / WW, w = i - r * WW;
        float s0 = 0.f, s1 = 0.f;
#pragma unroll
        for (int t = 0; t < 9; ++t) {
            float m = sm[r][w + t], f = sf[r][w + t];
            s0 += m * m; s1 += f * f;
        }
        wsum[0][r][w] = s0; wsum[1][r][w] = s1;
    }
    __syncthreads();
    for (int i = tid; i < HT * WW; i += 256) {
        int ro = i / WW, w = i - ro * WW;
        float a0 = 0.f, a1 = 0.f;
#pragma unroll
        for (int t = 0; t < 9; ++t) {
            a0 += wsum[0][ro + t][w];
            a1 += wsum[1][ro + t][w];
        }
        int go = (d * HH + h0 + ro) * WW + w;
        out[2 * VOL + go] = a0;
        out[3 * VOL + go] = a1;
    }
}

// ---------------------------------------------------------------------------
// Kernel 2: sliding-window D-sum + per-voxel cc + block reduction.
// Thread owns one (h,w) column over a DCH-deep d-chunk; 5 running sums in
// registers; add plane d+5 (HBM), subtract plane d-4 (L1/L2 hit, 45KB back).
// ---------------------------------------------------------------------------
__global__ __launch_bounds__(256) void ncc_dred(const float* __restrict__ s5,
                                                float* __restrict__ partial) {
    const int hw = blockIdx.x * 256 + threadIdx.x;   // 0..25599
    const int d0 = blockIdx.y * DCH;
    const float* p0 = s5 + hw;

    float s0 = 0.f, s1 = 0.f, s2 = 0.f, s3 = 0.f, s4 = 0.f;
    // warm-up: planes [d0-4, d0+4] clipped
    {
        int lo = d0 - 4 > 0 ? d0 - 4 : 0;
        int hi = d0 + 4 < DD - 1 ? d0 + 4 : DD - 1;
        for (int dd = lo; dd <= hi; ++dd) {
            const float* p = p0 + (size_t)dd * PLANE;
            s0 += p[0 * VOL]; s1 += p[1 * VOL]; s2 += p[2 * VOL];
            s3 += p[3 * VOL]; s4 += p[4 * VOL];
        }
    }

    float acc = 0.f;
    const float win = 729.0f, inv_win = 1.0f / 729.0f;
    for (int d = d0; d < d0 + DCH; ++d) {
        float up = s0 * inv_win, ut = s1 * inv_win;
        float cross = s4 - ut * s0 - up * s1 + up * ut * win;
        float pv = s2 - 2.0f * up * s0 + up * up * win;
        float tv = s3 - 2.0f * ut * s1 + ut * ut * win;
        pv = fmaxf(pv, 0.f);
        tv = fmaxf(tv, 0.f);
        float cc = cross * cross / (pv * tv + 0.001f);
        acc += fminf(fmaxf(cc, 0.f), 1.f);

        if (d + 1 < d0 + DCH) {
            if (d + 5 < DD) {
                const float* p = p0 + (size_t)(d + 5) * PLANE;
                s0 += p[0 * VOL]; s1 += p[1 * VOL]; s2 += p[2 * VOL];
                s3 += p[3 * VOL]; s4 += p[4 * VOL];
            }
            if (d - 4 >= 0) {
                const float* p = p0 + (size_t)(d - 4) * PLANE;
                s0 -= p[0 * VOL]; s1 -= p[1 * VOL]; s2 -= p[2 * VOL];
                s3 -= p[3 * VOL]; s4 -= p[4 * VOL];
            }
        }
    }

    for (int o = 32; o > 0; o >>= 1) acc += __shfl_down(acc, o, 64);
    __shared__ float red[4];
    int lane = threadIdx.x & 63, wid = threadIdx.x >> 6;
    if (lane == 0) red[wid] = acc;
    __syncthreads();
    if (threadIdx.x == 0)
        partial[blockIdx.y * HWT + blockIdx.x] = red[0] + red[1] + red[2] + red[3];
}

// ---------------------------------------------------------------------------
// Kernel 3: L1 gradient penalty on flow — float4 vectorized.
// 160 % 4 == 0 -> a float4 never crosses a row; h/d conditions uniform per f4.
// ---------------------------------------------------------------------------
__global__ __launch_bounds__(256) void grad_red(const float* __restrict__ fl,
                                                float* __restrict__ partial) {
    const int n4 = NB * 3 * VOL / 4;   // 6,144,000
    const float4* fl4 = (const float4*)fl;
    float acc = 0.f;
    const int stride = gridDim.x * blockDim.x;
    for (int i4 = blockIdx.x * blockDim.x + threadIdx.x; i4 < n4; i4 += stride) {
        const int idx = i4 * 4;
        const float4 v = fl4[i4];
        int w4 = idx % WW;
        int t  = idx / WW;
        int h  = t % HH;
        int d  = (t / HH) % DD;

        float a = fabsf(v.y - v.x) + fabsf(v.z - v.y) + fabsf(v.w - v.z);
        if (w4 < WW - 4) a += fabsf(fl[idx + 4] - v.w);
        if (h < HH - 1) {
            const float4 vh = fl4[i4 + WW / 4];
            a += fabsf(vh.x - v.x) + fabsf(vh.y - v.y) +
                 fabsf(vh.z - v.z) + fabsf(vh.w - v.w);
        }
        if (d < DD - 1) {
            const float4 vd = fl4[i4 + PLANE / 4];
            a += fabsf(vd.x - v.x) + fabsf(vd.y - v.y) +
                 fabsf(vd.z - v.z) + fabsf(vd.w - v.w);
        }
        acc += a;
    }
    for (int o = 32; o > 0; o >>= 1) acc += __shfl_down(acc, o, 64);
    __shared__ float red[4];
    int lane = threadIdx.x & 63, wid = threadIdx.x >> 6;
    if (lane == 0) red[wid] = acc;
    __syncthreads();
    if (threadIdx.x == 0) partial[blockIdx.x] = red[0] + red[1] + red[2] + red[3];
}

// ---------------------------------------------------------------------------
// Kernel 4: final deterministic reduction of partials -> scalar loss
// ---------------------------------------------------------------------------
__global__ __launch_bounds__(256) void finalize(const float* __restrict__ pcc, int ncc,
                                                const float* __restrict__ pg, int ng,
                                                float* __restrict__ out) {
    __shared__ float red[4];
    int lane = threadIdx.x & 63, wid = threadIdx.x >> 6;

    float a = 0.f;
    for (int i = threadIdx.x; i < ncc; i += 256) a += pcc[i];
    for (int o = 32; o > 0; o >>= 1) a += __shfl_down(a, o, 64);
    if (lane == 0) red[wid] = a;
    __syncthreads();
    float asum = red[0] + red[1] + red[2] + red[3];
    __syncthreads();

    float g = 0.f;
    for (int i = threadIdx.x; i < ng; i += 256) g += pg[i];
    for (int o = 32; o > 0; o >>= 1) g += __shfl_down(g, o, 64);
    if (lane == 0) red[wid] = g;
    __syncthreads();
    float gsum = red[0] + red[1] + red[2] + red[3];

    if (threadIdx.x == 0) {
        float sim = 1.0f - asum / 8192000.0f;          // mean over (2,1,160,160,160)
        float reg = gsum / 73267200.0f;                // 3 * (2*3*159*160*160)
        out[0] = sim + reg;
    }
}

// ---------------------------------------------------------------------------
extern "C" void kernel_launch(void* const* d_in, const int* in_sizes, int n_in,
                              void* d_out, int out_size, void* d_ws, size_t ws_size,
                              hipStream_t stream) {
    const float* moved  = (const float*)d_in[0];
    const float* fixedp = (const float*)d_in[1];
    const float* flow   = (const float*)d_in[2];
    float* out = (float*)d_out;
    float* ws  = (float*)d_ws;

    float* fields = ws;                              // 5*VOL floats (81.9 MB)
    float* pcc    = ws + 5 * (size_t)VOL;            // NB*DREDBLK floats
    float* pg     = pcc + NB * DREDBLK;              // GBLOCKS floats

    grad_red<<<GBLOCKS, 256, 0, stream>>>(flow, pg);

    for (int b = 0; b < NB; ++b) {
        ncc_wh<<<dim3(HH / HT, DD), 256, 0, stream>>>(
            moved + (size_t)b * VOL, fixedp + (size_t)b * VOL, fields);
        ncc_dred<<<dim3(HWT, NDCH), 256, 0, stream>>>(fields, pcc + b * DREDBLK);
    }

    finalize<<<1, 256, 0, stream>>>(pcc, NB * DREDBLK, pg, GBLOCKS, out);
}

// Round 3
// 163.647 us; speedup vs baseline: 1.4650x; 1.2044x over previous
//
#include <hip/hip_runtime.h>

#define DD 160
#define HH 160
#define WW 160
#define VOL (DD * HH * WW)   // per-batch volume = 4,096,000
#define PLANE (HH * WW)      // 25,600
#define NB 2
#define DCH 20               // d-outputs per ncc_dred block
#define NDCH (DD / DCH)      // 8
#define HWT (PLANE / 256)    // 100 hw-tiles
#define DREDBLK (HWT * NDCH) // 800 blocks per batch
#define GBLOCKS 2048

// ---------------------------------------------------------------------------
// Kernel 1 (v2): fused W+H box sums of the 5 moment fields via register
// sliding windows.  fields: 0:m 1:f 2:m*m 3:f*f 4:m*f
// Block: output tile 8h x 160w at one d.  Grid (20, 160).
// W-stage: thread (r,s) = (tid>>4, tid&15) owns staged row r (h0-4+r) and
//   10 outputs w=10s..10s+9; loads 5 float4 per field from GLOBAL (halo rows
//   are L1/L2 hits), slides 5 running sums, writes wsum[5][16][161] in LDS.
// H-stage: 800 tasks (w,field); slide 9-row window down the column,
//   8 coalesced global stores each.
// ---------------------------------------------------------------------------
__global__ __launch_bounds__(256) void ncc_wh(const float* __restrict__ mv,
                                              const float* __restrict__ fx,
                                              float* __restrict__ out) {
    __shared__ float wsum[5][16][161];

    const int d   = blockIdx.y;
    const int h0  = blockIdx.x * 8;
    const int tid = threadIdx.x;
    const int r   = tid >> 4;          // 0..15 staged row
    const int s   = tid & 15;          // 0..15 w-segment
    const int h   = h0 - 4 + r;
    const int w0  = 10 * s;
    const int a   = (w0 - 4) & ~3;     // float4-aligned window start (may be -4)
    const int off = (w0 - 4) - a;      // 0 or 2

    float vm[20], vf[20];
#pragma unroll
    for (int i = 0; i < 20; ++i) { vm[i] = 0.f; vf[i] = 0.f; }

    const bool rowok = (unsigned)h < (unsigned)HH;
    const float* rowm = mv + ((size_t)d * HH + h) * WW;
    const float* rowf = fx + ((size_t)d * HH + h) * WW;
    if (rowok) {
#pragma unroll
        for (int j = 0; j < 5; ++j) {
            int w4 = a + 4 * j;
            if (w4 >= 0 && w4 <= WW - 4) {
                float4 m4 = *(const float4*)(rowm + w4);
                float4 f4 = *(const float4*)(rowf + w4);
                vm[4*j] = m4.x; vm[4*j+1] = m4.y; vm[4*j+2] = m4.z; vm[4*j+3] = m4.w;
                vf[4*j] = f4.x; vf[4*j+1] = f4.y; vf[4*j+2] = f4.z; vf[4*j+3] = f4.w;
            } else {
#pragma unroll
                for (int e = 0; e < 4; ++e) {
                    int w = w4 + e;
                    if ((unsigned)w < (unsigned)WW) {
                        vm[4*j+e] = rowm[w];
                        vf[4*j+e] = rowf[w];
                    }
                }
            }
        }
    }

    // initial 9-tap window for wout = w0
    float sm = 0.f, sf = 0.f, smm = 0.f, sff = 0.f, smf = 0.f;
#pragma unroll
    for (int i = 0; i < 9; ++i) {
        float m = vm[off + i], f = vf[off + i];
        sm += m; sf += f;
        smm = fmaf(m, m, smm);
        sff = fmaf(f, f, sff);
        smf = fmaf(m, f, smf);
    }
    wsum[0][r][w0] = sm; wsum[1][r][w0] = sf;
    wsum[2][r][w0] = smm; wsum[3][r][w0] = sff; wsum[4][r][w0] = smf;
#pragma unroll
    for (int k = 1; k < 10; ++k) {
        float am = vm[off + 8 + k], af = vf[off + 8 + k];
        float bm = vm[off + k - 1], bf = vf[off + k - 1];
        sm  += am - bm;
        sf  += af - bf;
        smm += am * am - bm * bm;
        sff += af * af - bf * bf;
        smf += am * af - bm * bf;
        wsum[0][r][w0 + k] = sm; wsum[1][r][w0 + k] = sf;
        wsum[2][r][w0 + k] = smm; wsum[3][r][w0 + k] = sff; wsum[4][r][w0 + k] = smf;
    }
    __syncthreads();

    // H-stage: slide 9-row window down each (w, field) column
    for (int i = tid; i < 5 * WW; i += 256) {
        int f = i / WW, w = i - f * WW;
        float s9 = 0.f;
#pragma unroll
        for (int t = 0; t < 9; ++t) s9 += wsum[f][t][w];
        size_t go = (size_t)f * VOL + ((size_t)d * HH + h0) * WW + w;
        out[go] = s9;
#pragma unroll
        for (int ro = 1; ro < 8; ++ro) {
            s9 += wsum[f][ro + 8][w] - wsum[f][ro - 1][w];
            out[go + (size_t)ro * WW] = s9;
        }
    }
}

// ---------------------------------------------------------------------------
// Kernel 2: sliding-window D-sum + per-voxel cc + block reduction.
// ---------------------------------------------------------------------------
__global__ __launch_bounds__(256) void ncc_dred(const float* __restrict__ s5,
                                                float* __restrict__ partial) {
    const int hw = blockIdx.x * 256 + threadIdx.x;   // 0..25599
    const int d0 = blockIdx.y * DCH;
    const float* p0 = s5 + hw;

    float s0 = 0.f, s1 = 0.f, s2 = 0.f, s3 = 0.f, s4 = 0.f;
    {
        int lo = d0 - 4 > 0 ? d0 - 4 : 0;
        int hi = d0 + 4 < DD - 1 ? d0 + 4 : DD - 1;
        for (int dd = lo; dd <= hi; ++dd) {
            const float* p = p0 + (size_t)dd * PLANE;
            s0 += p[0 * VOL]; s1 += p[1 * VOL]; s2 += p[2 * VOL];
            s3 += p[3 * VOL]; s4 += p[4 * VOL];
        }
    }

    float acc = 0.f;
    const float win = 729.0f, inv_win = 1.0f / 729.0f;
    for (int d = d0; d < d0 + DCH; ++d) {
        float up = s0 * inv_win, ut = s1 * inv_win;
        float cross = s4 - ut * s0 - up * s1 + up * ut * win;
        float pv = s2 - 2.0f * up * s0 + up * up * win;
        float tv = s3 - 2.0f * ut * s1 + ut * ut * win;
        pv = fmaxf(pv, 0.f);
        tv = fmaxf(tv, 0.f);
        float cc = cross * cross / (pv * tv + 0.001f);
        acc += fminf(fmaxf(cc, 0.f), 1.f);

        if (d + 1 < d0 + DCH) {
            if (d + 5 < DD) {
                const float* p = p0 + (size_t)(d + 5) * PLANE;
                s0 += p[0 * VOL]; s1 += p[1 * VOL]; s2 += p[2 * VOL];
                s3 += p[3 * VOL]; s4 += p[4 * VOL];
            }
            if (d - 4 >= 0) {
                const float* p = p0 + (size_t)(d - 4) * PLANE;
                s0 -= p[0 * VOL]; s1 -= p[1 * VOL]; s2 -= p[2 * VOL];
                s3 -= p[3 * VOL]; s4 -= p[4 * VOL];
            }
        }
    }

    for (int o = 32; o > 0; o >>= 1) acc += __shfl_down(acc, o, 64);
    __shared__ float red[4];
    int lane = threadIdx.x & 63, wid = threadIdx.x >> 6;
    if (lane == 0) red[wid] = acc;
    __syncthreads();
    if (threadIdx.x == 0)
        partial[blockIdx.y * HWT + blockIdx.x] = red[0] + red[1] + red[2] + red[3];
}

// ---------------------------------------------------------------------------
// Kernel 3: L1 gradient penalty on flow — float4 vectorized.
// ---------------------------------------------------------------------------
__global__ __launch_bounds__(256) void grad_red(const float* __restrict__ fl,
                                                float* __restrict__ partial) {
    const int n4 = NB * 3 * VOL / 4;   // 6,144,000
    const float4* fl4 = (const float4*)fl;
    float acc = 0.f;
    const int stride = gridDim.x * blockDim.x;
    for (int i4 = blockIdx.x * blockDim.x + threadIdx.x; i4 < n4; i4 += stride) {
        const int idx = i4 * 4;
        const float4 v = fl4[i4];
        int w4 = idx % WW;
        int t  = idx / WW;
        int h  = t % HH;
        int d  = (t / HH) % DD;

        float a = fabsf(v.y - v.x) + fabsf(v.z - v.y) + fabsf(v.w - v.z);
        if (w4 < WW - 4) a += fabsf(fl[idx + 4] - v.w);
        if (h < HH - 1) {
            const float4 vh = fl4[i4 + WW / 4];
            a += fabsf(vh.x - v.x) + fabsf(vh.y - v.y) +
                 fabsf(vh.z - v.z) + fabsf(vh.w - v.w);
        }
        if (d < DD - 1) {
            const float4 vd = fl4[i4 + PLANE / 4];
            a += fabsf(vd.x - v.x) + fabsf(vd.y - v.y) +
                 fabsf(vd.z - v.z) + fabsf(vd.w - v.w);
        }
        acc += a;
    }
    for (int o = 32; o > 0; o >>= 1) acc += __shfl_down(acc, o, 64);
    __shared__ float red[4];
    int lane = threadIdx.x & 63, wid = threadIdx.x >> 6;
    if (lane == 0) red[wid] = acc;
    __syncthreads();
    if (threadIdx.x == 0) partial[blockIdx.x] = red[0] + red[1] + red[2] + red[3];
}

// ---------------------------------------------------------------------------
// Kernel 4: final deterministic reduction of partials -> scalar loss
// ---------------------------------------------------------------------------
__global__ __launch_bounds__(256) void finalize(const float* __restrict__ pcc, int ncc,
                                                const float* __restrict__ pg, int ng,
                                                float* __restrict__ out) {
    __shared__ float red[4];
    int lane = threadIdx.x & 63, wid = threadIdx.x >> 6;

    float a = 0.f;
    for (int i = threadIdx.x; i < ncc; i += 256) a += pcc[i];
    for (int o = 32; o > 0; o >>= 1) a += __shfl_down(a, o, 64);
    if (lane == 0) red[wid] = a;
    __syncthreads();
    float asum = red[0] + red[1] + red[2] + red[3];
    __syncthreads();

    float g = 0.f;
    for (int i = threadIdx.x; i < ng; i += 256) g += pg[i];
    for (int o = 32; o > 0; o >>= 1) g += __shfl_down(g, o, 64);
    if (lane == 0) red[wid] = g;
    __syncthreads();
    float gsum = red[0] + red[1] + red[2] + red[3];

    if (threadIdx.x == 0) {
        float sim = 1.0f - asum / 8192000.0f;          // mean over (2,1,160,160,160)
        float reg = gsum / 73267200.0f;                // 3 * (2*3*159*160*160)
        out[0] = sim + reg;
    }
}

// ---------------------------------------------------------------------------
extern "C" void kernel_launch(void* const* d_in, const int* in_sizes, int n_in,
                              void* d_out, int out_size, void* d_ws, size_t ws_size,
                              hipStream_t stream) {
    const float* moved  = (const float*)d_in[0];
    const float* fixedp = (const float*)d_in[1];
    const float* flow   = (const float*)d_in[2];
    float* out = (float*)d_out;
    float* ws  = (float*)d_ws;

    float* fields = ws;                              // 5*VOL floats (81.9 MB)
    float* pcc    = ws + 5 * (size_t)VOL;            // NB*DREDBLK floats
    float* pg     = pcc + NB * DREDBLK;              // GBLOCKS floats

    grad_red<<<GBLOCKS, 256, 0, stream>>>(flow, pg);

    for (int b = 0; b < NB; ++b) {
        ncc_wh<<<dim3(HH / 8, DD), 256, 0, stream>>>(
            moved + (size_t)b * VOL, fixedp + (size_t)b * VOL, fields);
        ncc_dred<<<dim3(HWT, NDCH), 256, 0, stream>>>(fields, pcc + b * DREDBLK);
    }

    finalize<<<1, 256, 0, stream>>>(pcc, NB * DREDBLK, pg, GBLOCKS, out);
}

// Round 4
// 139.320 us; speedup vs baseline: 1.7209x; 1.1746x over previous
//
#include <hip/hip_runtime.h>

#define DD 160
#define HH 160
#define WW 160
#define VOL (DD * HH * WW)   // per-batch volume = 4,096,000
#define PLANE (HH * WW)      // 25,600
#define NB 2
#define HT 16                // output h-rows per wh block
#define HS (HT + 8)          // staged rows = 24
#define LDW 164              // LDS row stride (floats); 164*4B = 16B-aligned
#define DCH 20               // d-outputs per ncc_dred block
#define NDCH (DD / DCH)      // 8
#define HWT (PLANE / 256)    // 100 hw-tiles
#define DREDBLK (HWT * NDCH) // 800 per batch
#define GCHD 20              // grad d-chunk
#define GBLK (NB * 3 * (DD / GCHD) * HH * (WW / 4) / 256)   // 1200

// ---------------------------------------------------------------------------
// Kernel 1 (v3): fused W+H box sums of 5 moment fields, all-vector traffic.
// Block: 512 thr, output 16h x 160w at one (d, b). Grid (10, 160, 2).
// W-stage (480 thr): thread (r,s)=(t/20, t%20) owns staged row r (h0-4+r),
//   8 outputs w0=8s; 4 aligned float4 loads per image; 5 running sums slide;
//   2 ds_write_b128 per field.
// H-stage (400 thr): task (field, w-quad, row-half): 16 ds_read_b128 down the
//   column + 8 float4 global stores, sliding 9-row window.
// ---------------------------------------------------------------------------
__global__ __launch_bounds__(512, 4) void ncc_wh(const float* __restrict__ mv,
                                                 const float* __restrict__ fx,
                                                 float* __restrict__ out) {
    __shared__ float wsum[5][HS][LDW];

    const int d   = blockIdx.y;
    const int b   = blockIdx.z;
    const int h0  = blockIdx.x * HT;
    const int tid = threadIdx.x;

    if (tid < 480) {
        const int r  = tid / 20;        // 0..23 staged row
        const int s  = tid - r * 20;    // 0..19 w-segment
        const int h  = h0 - 4 + r;
        const int w0 = 8 * s;

        float vm[16], vf[16];
#pragma unroll
        for (int i = 0; i < 16; ++i) { vm[i] = 0.f; vf[i] = 0.f; }

        if ((unsigned)h < (unsigned)HH) {
            const float* rowm = mv + (size_t)b * VOL + ((size_t)d * HH + h) * WW;
            const float* rowf = fx + (size_t)b * VOL + ((size_t)d * HH + h) * WW;
#pragma unroll
            for (int j = 0; j < 4; ++j) {
                const int w4 = w0 - 4 + 4 * j;
                if (w4 >= 0 && w4 <= WW - 4) {
                    float4 m4 = *(const float4*)(rowm + w4);
                    float4 f4 = *(const float4*)(rowf + w4);
                    vm[4*j+0] = m4.x; vm[4*j+1] = m4.y; vm[4*j+2] = m4.z; vm[4*j+3] = m4.w;
                    vf[4*j+0] = f4.x; vf[4*j+1] = f4.y; vf[4*j+2] = f4.z; vf[4*j+3] = f4.w;
                } else {
#pragma unroll
                    for (int e = 0; e < 4; ++e) {
                        const int w = w4 + e;
                        if ((unsigned)w < (unsigned)WW) {
                            vm[4*j+e] = rowm[w];
                            vf[4*j+e] = rowf[w];
                        }
                    }
                }
            }
        }

        float o0[8], o1[8], o2[8], o3[8], o4[8];
        float sm = 0.f, sf = 0.f, smm = 0.f, sff = 0.f, smf = 0.f;
#pragma unroll
        for (int i = 0; i < 9; ++i) {
            float m = vm[i], f = vf[i];
            sm += m; sf += f;
            smm = fmaf(m, m, smm);
            sff = fmaf(f, f, sff);
            smf = fmaf(m, f, smf);
        }
        o0[0] = sm; o1[0] = sf; o2[0] = smm; o3[0] = sff; o4[0] = smf;
#pragma unroll
        for (int k = 1; k < 8; ++k) {
            float am = vm[k + 8], bm = vm[k - 1];
            float af = vf[k + 8], bf = vf[k - 1];
            sm  += am - bm;
            sf  += af - bf;
            smm += fmaf(am, am, -(bm * bm));
            sff += fmaf(af, af, -(bf * bf));
            smf += fmaf(am, af, -(bm * bf));
            o0[k] = sm; o1[k] = sf; o2[k] = smm; o3[k] = sff; o4[k] = smf;
        }
        *(float4*)&wsum[0][r][w0]     = *(float4*)&o0[0];
        *(float4*)&wsum[0][r][w0 + 4] = *(float4*)&o0[4];
        *(float4*)&wsum[1][r][w0]     = *(float4*)&o1[0];
        *(float4*)&wsum[1][r][w0 + 4] = *(float4*)&o1[4];
        *(float4*)&wsum[2][r][w0]     = *(float4*)&o2[0];
        *(float4*)&wsum[2][r][w0 + 4] = *(float4*)&o2[4];
        *(float4*)&wsum[3][r][w0]     = *(float4*)&o3[0];
        *(float4*)&wsum[3][r][w0 + 4] = *(float4*)&o3[4];
        *(float4*)&wsum[4][r][w0]     = *(float4*)&o4[0];
        *(float4*)&wsum[4][r][w0 + 4] = *(float4*)&o4[4];
    }
    __syncthreads();

    if (tid < 400) {
        const int f    = tid / 80;              // field 0..4
        const int rem  = tid - f * 80;
        const int half = rem / 40;              // 0..1
        const int w    = 4 * (rem - half * 40); // 0..156
        const int ro0  = 8 * half;

        float4 s9 = make_float4(0.f, 0.f, 0.f, 0.f);
#pragma unroll
        for (int t = 0; t < 9; ++t) {
            float4 v = *(const float4*)&wsum[f][ro0 + t][w];
            s9.x += v.x; s9.y += v.y; s9.z += v.z; s9.w += v.w;
        }
        float* ob = out + (size_t)(b * 5 + f) * VOL
                        + ((size_t)d * HH + h0 + ro0) * WW + w;
        *(float4*)ob = s9;
#pragma unroll
        for (int ro = 1; ro < 8; ++ro) {
            float4 aa = *(const float4*)&wsum[f][ro0 + ro + 8][w];
            float4 bb = *(const float4*)&wsum[f][ro0 + ro - 1][w];
            s9.x += aa.x - bb.x; s9.y += aa.y - bb.y;
            s9.z += aa.z - bb.z; s9.w += aa.w - bb.w;
            *(float4*)(ob + (size_t)ro * WW) = s9;
        }
    }
}

// ---------------------------------------------------------------------------
// Kernel 2: sliding-window D-sum + per-voxel cc + block reduction.
// Grid (100, 8, NB).
// ---------------------------------------------------------------------------
__global__ __launch_bounds__(256) void ncc_dred(const float* __restrict__ fields,
                                                float* __restrict__ partial) {
    const int hw = blockIdx.x * 256 + threadIdx.x;   // 0..25599
    const int d0 = blockIdx.y * DCH;
    const float* p0 = fields + (size_t)blockIdx.z * 5 * VOL + hw;

    float s0 = 0.f, s1 = 0.f, s2 = 0.f, s3 = 0.f, s4 = 0.f;
    {
        int lo = d0 - 4 > 0 ? d0 - 4 : 0;
        int hi = d0 + 4 < DD - 1 ? d0 + 4 : DD - 1;
        for (int dd = lo; dd <= hi; ++dd) {
            const float* p = p0 + (size_t)dd * PLANE;
            s0 += p[0 * VOL]; s1 += p[1 * VOL]; s2 += p[2 * VOL];
            s3 += p[3 * VOL]; s4 += p[4 * VOL];
        }
    }

    float acc = 0.f;
    const float win = 729.0f, inv_win = 1.0f / 729.0f;
    for (int d = d0; d < d0 + DCH; ++d) {
        float up = s0 * inv_win, ut = s1 * inv_win;
        float cross = s4 - ut * s0 - up * s1 + up * ut * win;
        float pv = s2 - 2.0f * up * s0 + up * up * win;
        float tv = s3 - 2.0f * ut * s1 + ut * ut * win;
        pv = fmaxf(pv, 0.f);
        tv = fmaxf(tv, 0.f);
        float cc = cross * cross / (pv * tv + 0.001f);
        acc += fminf(fmaxf(cc, 0.f), 1.f);

        if (d + 1 < d0 + DCH) {
            if (d + 5 < DD) {
                const float* p = p0 + (size_t)(d + 5) * PLANE;
                s0 += p[0 * VOL]; s1 += p[1 * VOL]; s2 += p[2 * VOL];
                s3 += p[3 * VOL]; s4 += p[4 * VOL];
            }
            if (d - 4 >= 0) {
                const float* p = p0 + (size_t)(d - 4) * PLANE;
                s0 -= p[0 * VOL]; s1 -= p[1 * VOL]; s2 -= p[2 * VOL];
                s3 -= p[3 * VOL]; s4 -= p[4 * VOL];
            }
        }
    }

    for (int o = 32; o > 0; o >>= 1) acc += __shfl_down(acc, o, 64);
    __shared__ float red[4];
    int lane = threadIdx.x & 63, wid = threadIdx.x >> 6;
    if (lane == 0) red[wid] = acc;
    __syncthreads();
    if (threadIdx.x == 0)
        partial[((size_t)blockIdx.z * NDCH + blockIdx.y) * HWT + blockIdx.x] =
            red[0] + red[1] + red[2] + red[3];
}

// ---------------------------------------------------------------------------
// Kernel 3 (v2): L1 gradient penalty — d-walking float4 chunks.
// Thread owns (bc, h, w-quad), walks GCHD d's; v(d+1) reused as next v.
// ---------------------------------------------------------------------------
__global__ __launch_bounds__(256) void grad_red(const float* __restrict__ fl,
                                                float* __restrict__ partial) {
    const int gid = blockIdx.x * 256 + threadIdx.x;  // 0..307199
    const int w4  = gid % 40;
    int t = gid / 40;
    const int h  = t % HH;  t /= HH;
    const int dc = t % (DD / GCHD); t /= (DD / GCHD);
    const int bc = t;                                // 0..5
    const int d0 = dc * GCHD;
    const int w  = w4 * 4;

    const float* base = fl + (size_t)bc * VOL;
    float acc = 0.f;
    float4 v = *(const float4*)(base + ((size_t)d0 * HH + h) * WW + w);
    for (int d = d0; d < d0 + GCHD; ++d) {
        const float* pd = base + ((size_t)d * HH + h) * WW + w;
        float4 vn = v;
        if (d < DD - 1) {
            vn = *(const float4*)(pd + PLANE);
            acc += fabsf(vn.x - v.x) + fabsf(vn.y - v.y) +
                   fabsf(vn.z - v.z) + fabsf(vn.w - v.w);
        }
        if (h < HH - 1) {
            float4 vh = *(const float4*)(pd + WW);
            acc += fabsf(vh.x - v.x) + fabsf(vh.y - v.y) +
                   fabsf(vh.z - v.z) + fabsf(vh.w - v.w);
        }
        acc += fabsf(v.y - v.x) + fabsf(v.z - v.y) + fabsf(v.w - v.z);
        if (w < WW - 4) acc += fabsf(pd[4] - v.w);
        v = vn;
    }

    for (int o = 32; o > 0; o >>= 1) acc += __shfl_down(acc, o, 64);
    __shared__ float red[4];
    int lane = threadIdx.x & 63, wid = threadIdx.x >> 6;
    if (lane == 0) red[wid] = acc;
    __syncthreads();
    if (threadIdx.x == 0) partial[blockIdx.x] = red[0] + red[1] + red[2] + red[3];
}

// ---------------------------------------------------------------------------
// Kernel 4: final deterministic reduction of partials -> scalar loss
// ---------------------------------------------------------------------------
__global__ __launch_bounds__(256) void finalize(const float* __restrict__ pcc, int ncc,
                                                const float* __restrict__ pg, int ng,
                                                float* __restrict__ out) {
    __shared__ float red[4];
    int lane = threadIdx.x & 63, wid = threadIdx.x >> 6;

    float a = 0.f;
    for (int i = threadIdx.x; i < ncc; i += 256) a += pcc[i];
    for (int o = 32; o > 0; o >>= 1) a += __shfl_down(a, o, 64);
    if (lane == 0) red[wid] = a;
    __syncthreads();
    float asum = red[0] + red[1] + red[2] + red[3];
    __syncthreads();

    float g = 0.f;
    for (int i = threadIdx.x; i < ng; i += 256) g += pg[i];
    for (int o = 32; o > 0; o >>= 1) g += __shfl_down(g, o, 64);
    if (lane == 0) red[wid] = g;
    __syncthreads();
    float gsum = red[0] + red[1] + red[2] + red[3];

    if (threadIdx.x == 0) {
        float sim = 1.0f - asum / 8192000.0f;          // mean over (2,1,160,160,160)
        float reg = gsum / 73267200.0f;                // 3 * (2*3*159*160*160)
        out[0] = sim + reg;
    }
}

// ---------------------------------------------------------------------------
extern "C" void kernel_launch(void* const* d_in, const int* in_sizes, int n_in,
                              void* d_out, int out_size, void* d_ws, size_t ws_size,
                              hipStream_t stream) {
    const float* moved  = (const float*)d_in[0];
    const float* fixedp = (const float*)d_in[1];
    const float* flow   = (const float*)d_in[2];
    float* out = (float*)d_out;
    float* ws  = (float*)d_ws;

    float* fields = ws;                               // NB*5*VOL floats (163.8 MB)
    float* pcc    = ws + (size_t)NB * 5 * VOL;        // NB*DREDBLK floats
    float* pg     = pcc + NB * DREDBLK;               // GBLK floats

    grad_red<<<GBLK, 256, 0, stream>>>(flow, pg);
    ncc_wh<<<dim3(HH / HT, DD, NB), 512, 0, stream>>>(moved, fixedp, fields);
    ncc_dred<<<dim3(HWT, NDCH, NB), 256, 0, stream>>>(fields, pcc);
    finalize<<<1, 256, 0, stream>>>(pcc, NB * DREDBLK, pg, GBLK, out);
}

// Round 5
// 97.652 us; speedup vs baseline: 2.4552x; 1.4267x over previous
//
#include <hip/hip_runtime.h>

#define DD 160
#define HH 160
#define WW 160
#define VOL (DD * HH * WW)   // per-batch volume = 4,096,000
#define PLANE (HH * WW)      // 25,600
#define NB 2
#define HT 16                // output h-rows per wh block
#define HS (HT + 8)          // staged rows = 24
#define LDW 164              // LDS row stride (floats); 16B-aligned
#define DCH 20               // d-outputs per ncc_dred block
#define NDCH (DD / DCH)      // 8
#define CPT 50               // column-pair tiles: 12800 pairs / 256
#define DREDBLK (CPT * NDCH) // 400 per batch
#define GCHD 20              // grad d-chunk
#define GBLK (NB * 3 * (DD / GCHD) * HH * (WW / 4) / 256)   // 1200

typedef _Float16 h4 __attribute__((ext_vector_type(4)));
typedef _Float16 h2 __attribute__((ext_vector_type(2)));

// ---------------------------------------------------------------------------
// Kernel 1 (v4): fused W+H box sums of 5 moment fields -> fp16 fields.
// Block: 512 thr, output 16h x 160w at one (d, b). Grid (10, 160, 2).
// ---------------------------------------------------------------------------
__global__ __launch_bounds__(512, 4) void ncc_wh(const float* __restrict__ mv,
                                                 const float* __restrict__ fx,
                                                 _Float16* __restrict__ out) {
    __shared__ float wsum[5][HS][LDW];

    const int d   = blockIdx.y;
    const int b   = blockIdx.z;
    const int h0  = blockIdx.x * HT;
    const int tid = threadIdx.x;

    if (tid < 480) {
        const int r  = tid / 20;        // 0..23 staged row
        const int s  = tid - r * 20;    // 0..19 w-segment
        const int h  = h0 - 4 + r;
        const int w0 = 8 * s;

        float vm[16], vf[16];
#pragma unroll
        for (int i = 0; i < 16; ++i) { vm[i] = 0.f; vf[i] = 0.f; }

        if ((unsigned)h < (unsigned)HH) {
            const float* rowm = mv + (size_t)b * VOL + ((size_t)d * HH + h) * WW;
            const float* rowf = fx + (size_t)b * VOL + ((size_t)d * HH + h) * WW;
#pragma unroll
            for (int j = 0; j < 4; ++j) {
                const int w4 = w0 - 4 + 4 * j;
                if (w4 >= 0 && w4 <= WW - 4) {
                    float4 m4 = *(const float4*)(rowm + w4);
                    float4 f4 = *(const float4*)(rowf + w4);
                    vm[4*j+0] = m4.x; vm[4*j+1] = m4.y; vm[4*j+2] = m4.z; vm[4*j+3] = m4.w;
                    vf[4*j+0] = f4.x; vf[4*j+1] = f4.y; vf[4*j+2] = f4.z; vf[4*j+3] = f4.w;
                } else {
#pragma unroll
                    for (int e = 0; e < 4; ++e) {
                        const int w = w4 + e;
                        if ((unsigned)w < (unsigned)WW) {
                            vm[4*j+e] = rowm[w];
                            vf[4*j+e] = rowf[w];
                        }
                    }
                }
            }
        }

        float o0[8], o1[8], o2[8], o3[8], o4[8];
        float sm = 0.f, sf = 0.f, smm = 0.f, sff = 0.f, smf = 0.f;
#pragma unroll
        for (int i = 0; i < 9; ++i) {
            float m = vm[i], f = vf[i];
            sm += m; sf += f;
            smm = fmaf(m, m, smm);
            sff = fmaf(f, f, sff);
            smf = fmaf(m, f, smf);
        }
        o0[0] = sm; o1[0] = sf; o2[0] = smm; o3[0] = sff; o4[0] = smf;
#pragma unroll
        for (int k = 1; k < 8; ++k) {
            float am = vm[k + 8], bm = vm[k - 1];
            float af = vf[k + 8], bf = vf[k - 1];
            sm  += am - bm;
            sf  += af - bf;
            smm += fmaf(am, am, -(bm * bm));
            sff += fmaf(af, af, -(bf * bf));
            smf += fmaf(am, af, -(bm * bf));
            o0[k] = sm; o1[k] = sf; o2[k] = smm; o3[k] = sff; o4[k] = smf;
        }
        *(float4*)&wsum[0][r][w0]     = *(float4*)&o0[0];
        *(float4*)&wsum[0][r][w0 + 4] = *(float4*)&o0[4];
        *(float4*)&wsum[1][r][w0]     = *(float4*)&o1[0];
        *(float4*)&wsum[1][r][w0 + 4] = *(float4*)&o1[4];
        *(float4*)&wsum[2][r][w0]     = *(float4*)&o2[0];
        *(float4*)&wsum[2][r][w0 + 4] = *(float4*)&o2[4];
        *(float4*)&wsum[3][r][w0]     = *(float4*)&o3[0];
        *(float4*)&wsum[3][r][w0 + 4] = *(float4*)&o3[4];
        *(float4*)&wsum[4][r][w0]     = *(float4*)&o4[0];
        *(float4*)&wsum[4][r][w0 + 4] = *(float4*)&o4[4];
    }
    __syncthreads();

    if (tid < 400) {
        const int f    = tid / 80;              // field 0..4
        const int rem  = tid - f * 80;
        const int half = rem / 40;              // 0..1
        const int w    = 4 * (rem - half * 40); // 0..156
        const int ro0  = 8 * half;

        float4 s9 = make_float4(0.f, 0.f, 0.f, 0.f);
#pragma unroll
        for (int t = 0; t < 9; ++t) {
            float4 v = *(const float4*)&wsum[f][ro0 + t][w];
            s9.x += v.x; s9.y += v.y; s9.z += v.z; s9.w += v.w;
        }
        _Float16* ob = out + (size_t)(b * 5 + f) * VOL
                           + ((size_t)d * HH + h0 + ro0) * WW + w;
        h4 o;
        o.x = (_Float16)s9.x; o.y = (_Float16)s9.y;
        o.z = (_Float16)s9.z; o.w = (_Float16)s9.w;
        *(h4*)ob = o;
#pragma unroll
        for (int ro = 1; ro < 8; ++ro) {
            float4 aa = *(const float4*)&wsum[f][ro0 + ro + 8][w];
            float4 bb = *(const float4*)&wsum[f][ro0 + ro - 1][w];
            s9.x += aa.x - bb.x; s9.y += aa.y - bb.y;
            s9.z += aa.z - bb.z; s9.w += aa.w - bb.w;
            o.x = (_Float16)s9.x; o.y = (_Float16)s9.y;
            o.z = (_Float16)s9.z; o.w = (_Float16)s9.w;
            *(h4*)(ob + (size_t)ro * WW) = o;
        }
    }
}

// ---------------------------------------------------------------------------
// Kernel 2 (v2): sliding-window D-sum on fp16 fields, 2 columns/thread.
// Grid (50, 8, NB).
// ---------------------------------------------------------------------------
__global__ __launch_bounds__(256) void ncc_dred(const _Float16* __restrict__ fields,
                                                float* __restrict__ partial) {
    const int hw = (blockIdx.x * 256 + threadIdx.x) * 2;   // 0..25598 even
    const int d0 = blockIdx.y * DCH;
    const _Float16* p0 = fields + (size_t)blockIdx.z * 5 * VOL + hw;

    float s0a = 0.f, s1a = 0.f, s2a = 0.f, s3a = 0.f, s4a = 0.f;
    float s0b = 0.f, s1b = 0.f, s2b = 0.f, s3b = 0.f, s4b = 0.f;
    {
        int lo = d0 - 4 > 0 ? d0 - 4 : 0;
        int hi = d0 + 4 < DD - 1 ? d0 + 4 : DD - 1;
        for (int dd = lo; dd <= hi; ++dd) {
            const _Float16* p = p0 + (size_t)dd * PLANE;
            h2 v0 = *(const h2*)(p + 0 * (size_t)VOL);
            h2 v1 = *(const h2*)(p + 1 * (size_t)VOL);
            h2 v2 = *(const h2*)(p + 2 * (size_t)VOL);
            h2 v3 = *(const h2*)(p + 3 * (size_t)VOL);
            h2 v4 = *(const h2*)(p + 4 * (size_t)VOL);
            s0a += (float)v0.x; s0b += (float)v0.y;
            s1a += (float)v1.x; s1b += (float)v1.y;
            s2a += (float)v2.x; s2b += (float)v2.y;
            s3a += (float)v3.x; s3b += (float)v3.y;
            s4a += (float)v4.x; s4b += (float)v4.y;
        }
    }

    float acc = 0.f;
    const float inv_win = 1.0f / 729.0f;
    for (int d = d0; d < d0 + DCH; ++d) {
        {   // col a
            float cross = fmaf(-(s0a * s1a), inv_win, s4a);
            float pv = fmaxf(fmaf(-(s0a * s0a), inv_win, s2a), 0.f);
            float tv = fmaxf(fmaf(-(s1a * s1a), inv_win, s3a), 0.f);
            float cc = cross * cross / (pv * tv + 0.001f);
            acc += fminf(fmaxf(cc, 0.f), 1.f);
        }
        {   // col b
            float cross = fmaf(-(s0b * s1b), inv_win, s4b);
            float pv = fmaxf(fmaf(-(s0b * s0b), inv_win, s2b), 0.f);
            float tv = fmaxf(fmaf(-(s1b * s1b), inv_win, s3b), 0.f);
            float cc = cross * cross / (pv * tv + 0.001f);
            acc += fminf(fmaxf(cc, 0.f), 1.f);
        }

        if (d + 1 < d0 + DCH) {
            if (d + 5 < DD) {
                const _Float16* p = p0 + (size_t)(d + 5) * PLANE;
                h2 v0 = *(const h2*)(p + 0 * (size_t)VOL);
                h2 v1 = *(const h2*)(p + 1 * (size_t)VOL);
                h2 v2 = *(const h2*)(p + 2 * (size_t)VOL);
                h2 v3 = *(const h2*)(p + 3 * (size_t)VOL);
                h2 v4 = *(const h2*)(p + 4 * (size_t)VOL);
                s0a += (float)v0.x; s0b += (float)v0.y;
                s1a += (float)v1.x; s1b += (float)v1.y;
                s2a += (float)v2.x; s2b += (float)v2.y;
                s3a += (float)v3.x; s3b += (float)v3.y;
                s4a += (float)v4.x; s4b += (float)v4.y;
            }
            if (d - 4 >= 0) {
                const _Float16* p = p0 + (size_t)(d - 4) * PLANE;
                h2 v0 = *(const h2*)(p + 0 * (size_t)VOL);
                h2 v1 = *(const h2*)(p + 1 * (size_t)VOL);
                h2 v2 = *(const h2*)(p + 2 * (size_t)VOL);
                h2 v3 = *(const h2*)(p + 3 * (size_t)VOL);
                h2 v4 = *(const h2*)(p + 4 * (size_t)VOL);
                s0a -= (float)v0.x; s0b -= (float)v0.y;
                s1a -= (float)v1.x; s1b -= (float)v1.y;
                s2a -= (float)v2.x; s2b -= (float)v2.y;
                s3a -= (float)v3.x; s3b -= (float)v3.y;
                s4a -= (float)v4.x; s4b -= (float)v4.y;
            }
        }
    }

    for (int o = 32; o > 0; o >>= 1) acc += __shfl_down(acc, o, 64);
    __shared__ float red[4];
    int lane = threadIdx.x & 63, wid = threadIdx.x >> 6;
    if (lane == 0) red[wid] = acc;
    __syncthreads();
    if (threadIdx.x == 0)
        partial[((size_t)blockIdx.z * NDCH + blockIdx.y) * CPT + blockIdx.x] =
            red[0] + red[1] + red[2] + red[3];
}

// ---------------------------------------------------------------------------
// Kernel 3: L1 gradient penalty — d-walking float4 chunks.
// ---------------------------------------------------------------------------
__global__ __launch_bounds__(256) void grad_red(const float* __restrict__ fl,
                                                float* __restrict__ partial) {
    const int gid = blockIdx.x * 256 + threadIdx.x;  // 0..307199
    const int w4  = gid % 40;
    int t = gid / 40;
    const int h  = t % HH;  t /= HH;
    const int dc = t % (DD / GCHD); t /= (DD / GCHD);
    const int bc = t;                                // 0..5
    const int d0 = dc * GCHD;
    const int w  = w4 * 4;

    const float* base = fl + (size_t)bc * VOL;
    float acc = 0.f;
    float4 v = *(const float4*)(base + ((size_t)d0 * HH + h) * WW + w);
    for (int d = d0; d < d0 + GCHD; ++d) {
        const float* pd = base + ((size_t)d * HH + h) * WW + w;
        float4 vn = v;
        if (d < DD - 1) {
            vn = *(const float4*)(pd + PLANE);
            acc += fabsf(vn.x - v.x) + fabsf(vn.y - v.y) +
                   fabsf(vn.z - v.z) + fabsf(vn.w - v.w);
        }
        if (h < HH - 1) {
            float4 vh = *(const float4*)(pd + WW);
            acc += fabsf(vh.x - v.x) + fabsf(vh.y - v.y) +
                   fabsf(vh.z - v.z) + fabsf(vh.w - v.w);
        }
        acc += fabsf(v.y - v.x) + fabsf(v.z - v.y) + fabsf(v.w - v.z);
        if (w < WW - 4) acc += fabsf(pd[4] - v.w);
        v = vn;
    }

    for (int o = 32; o > 0; o >>= 1) acc += __shfl_down(acc, o, 64);
    __shared__ float red[4];
    int lane = threadIdx.x & 63, wid = threadIdx.x >> 6;
    if (lane == 0) red[wid] = acc;
    __syncthreads();
    if (threadIdx.x == 0) partial[blockIdx.x] = red[0] + red[1] + red[2] + red[3];
}

// ---------------------------------------------------------------------------
// Kernel 4: final deterministic reduction of partials -> scalar loss
// ---------------------------------------------------------------------------
__global__ __launch_bounds__(256) void finalize(const float* __restrict__ pcc, int ncc,
                                                const float* __restrict__ pg, int ng,
                                                float* __restrict__ out) {
    __shared__ float red[4];
    int lane = threadIdx.x & 63, wid = threadIdx.x >> 6;

    float a = 0.f;
    for (int i = threadIdx.x; i < ncc; i += 256) a += pcc[i];
    for (int o = 32; o > 0; o >>= 1) a += __shfl_down(a, o, 64);
    if (lane == 0) red[wid] = a;
    __syncthreads();
    float asum = red[0] + red[1] + red[2] + red[3];
    __syncthreads();

    float g = 0.f;
    for (int i = threadIdx.x; i < ng; i += 256) g += pg[i];
    for (int o = 32; o > 0; o >>= 1) g += __shfl_down(g, o, 64);
    if (lane == 0) red[wid] = g;
    __syncthreads();
    float gsum = red[0] + red[1] + red[2] + red[3];

    if (threadIdx.x == 0) {
        float sim = 1.0f - asum / 8192000.0f;          // mean over (2,1,160,160,160)
        float reg = gsum / 73267200.0f;                // 3 * (2*3*159*160*160)
        out[0] = sim + reg;
    }
}

// ---------------------------------------------------------------------------
extern "C" void kernel_launch(void* const* d_in, const int* in_sizes, int n_in,
                              void* d_out, int out_size, void* d_ws, size_t ws_size,
                              hipStream_t stream) {
    const float* moved  = (const float*)d_in[0];
    const float* fixedp = (const float*)d_in[1];
    const float* flow   = (const float*)d_in[2];
    float* out = (float*)d_out;

    _Float16* fields = (_Float16*)d_ws;               // NB*5*VOL fp16 (81.9 MB)
    float* pcc = (float*)(fields + (size_t)NB * 5 * VOL);  // NB*DREDBLK floats
    float* pg  = pcc + NB * DREDBLK;                  // GBLK floats

    grad_red<<<GBLK, 256, 0, stream>>>(flow, pg);
    ncc_wh<<<dim3(HH / HT, DD, NB), 512, 0, stream>>>(moved, fixedp, fields);
    ncc_dred<<<dim3(CPT, NDCH, NB), 256, 0, stream>>>(fields, pcc);
    finalize<<<1, 256, 0, stream>>>(pcc, NB * DREDBLK, pg, GBLK, out);
}